// Round 3
// baseline (1415.834 us; speedup 1.0000x reference)
//
#include <hip/hip_runtime.h>
#include <stdint.h>
#include <math.h>

#define NB      8
#define NPTS    16384
#define NPOINT  512
#define NCH     128
#define KNBR    32
#define R2      0.04f

#define FPS_BPB   32                 // FPS blocks per batch
#define FPS_NBLK  (NB * FPS_BPB)     // 256 FPS blocks
#define PPB       (NPTS / FPS_BPB)   // 512 points per block
#define PPT       (PPB / 64)         // 8 points per thread

// ws layout
#define CENT_OFF   0                     // 8*512*4 = 16384 B
#define SLOTS_OFF  16384                 // 8 batches * 2 parity * 32 grp * 8B = 4096 B
#define FT_OFF     20480                 // transposed features

// argmax step over (value desc, index asc) using DPP permute (VALU latency)
#define DPP_ARG_STEP(v, p, CTRL) do {                                          \
    float _ov = __builtin_bit_cast(float, __builtin_amdgcn_update_dpp(         \
        __builtin_bit_cast(int, (v)), __builtin_bit_cast(int, (v)),            \
        (CTRL), 0xF, 0xF, false));                                             \
    int _op = __builtin_amdgcn_update_dpp((p), (p), (CTRL), 0xF, 0xF, false);  \
    bool _t = (_ov > (v)) || ((_ov == (v)) && (_op < (p)));                    \
    (v) = _t ? _ov : (v);                                                      \
    (p) = _t ? _op : (p);                                                      \
} while (0)

#define SHFL_ARG_STEP(v, p, XORAMT) do {                                       \
    float _ov = __shfl_xor((v), (XORAMT), 64);                                 \
    int   _op = __shfl_xor((p), (XORAMT), 64);                                 \
    bool _t = (_ov > (v)) || ((_ov == (v)) && (_op < (p)));                    \
    (v) = _t ? _ov : (v);                                                      \
    (p) = _t ? _op : (p);                                                      \
} while (0)

// -------- kernel 1: multi-block FPS (blocks 0..255) + feature transpose -----
// FPS: 32 one-wave blocks per batch, spin-synced per iteration through
// agent-scope 64-bit slots at the LLC. Slot = {tag[63:48]=iter,
// val_bits[47:16], (idx^0xFFFF)[15:0]} so u64 max == (val desc, idx asc).
// Parity-double-buffered slots make the missed-tag race impossible: a block
// reaches iteration i+2 (overwriting parity p) only after every block has
// exited poll(i) (it must observe all tag==i+1 stores, which happen after
// each block exits poll(i)).
__global__
__attribute__((amdgpu_flat_work_group_size(64, 64)))
void fps_transpose_kernel(const float* __restrict__ xyz,
                          const float* __restrict__ feat,
                          float* __restrict__ out,     // new_xyz at [0,12288)
                          int* __restrict__ cent,      // ws: 8*512 ints
                          unsigned long long* __restrict__ slots, // ws: 4 KB
                          float* __restrict__ ft,      // ws: (B,N,128) fp32
                          int use_ft)
{
    const int blk = blockIdx.x;
    const int tid = threadIdx.x;   // 0..63, one wave

    if (blk < FPS_NBLK) {
        const int b = blk >> 5;          // batch
        const int g = blk & 31;          // group within batch
        const float* xb = xyz + (size_t)b * NPTS * 3;
        unsigned long long* sb = slots + b * 64;   // [parity][32]

        // this block's 512 points: p = g*512 + k*64 + tid
        float px[PPT], py[PPT], pz[PPT], d[PPT];
#pragma unroll
        for (int k = 0; k < PPT; ++k) {
            int p = g * PPB + k * 64 + tid;
            px[k] = xb[p * 3 + 0];
            py[k] = xb[p * 3 + 1];
            pz[k] = xb[p * 3 + 2];
            d[k] = 1e10f;
        }
        float cx = xb[0], cy = xb[1], cz = xb[2];
        if (g == 0 && tid == 0) {
            cent[b * NPOINT + 0] = 0;
            out[((size_t)b * NPOINT + 0) * 3 + 0] = cx;
            out[((size_t)b * NPOINT + 0) * 3 + 1] = cy;
            out[((size_t)b * NPOINT + 0) * 3 + 2] = cz;
        }

        for (int i = 1; i < NPOINT; ++i) {
            // phase 1: min-distance update, value-only max tracking (exact:
            // same op order as reference, no contraction)
            float vmax = -1.0f;
#pragma unroll
            for (int k = 0; k < PPT; ++k) {
                float dx = __fsub_rn(px[k], cx);
                float dy = __fsub_rn(py[k], cy);
                float dz = __fsub_rn(pz[k], cz);
                float dd = __fadd_rn(__fadd_rn(__fmul_rn(dx, dx),
                                               __fmul_rn(dy, dy)),
                                     __fmul_rn(dz, dz));
                float nd = fminf(d[k], dd);     // np.minimum, exact
                d[k] = nd;
                vmax = fmaxf(vmax, nd);
            }
            // recover earliest k with d[k]==vmax (ascending k == ascending
            // global index -> reference tie-break)
            int bk = PPT - 1;
#pragma unroll
            for (int k = PPT - 2; k >= 0; --k) bk = (d[k] == vmax) ? k : bk;

            float rv = vmax;
            int   rp = g * PPB + bk * 64 + tid;   // global idx within batch
            // wave argmax (val desc, idx asc): 4 DPP + 2 shfl
            DPP_ARG_STEP(rv, rp, 0xB1);
            DPP_ARG_STEP(rv, rp, 0x4E);
            DPP_ARG_STEP(rv, rp, 0x141);
            DPP_ARG_STEP(rv, rp, 0x140);
            SHFL_ARG_STEP(rv, rp, 16);
            SHFL_ARG_STEP(rv, rp, 32);

            const int parity = i & 1;
            unsigned long long* sp = sb + parity * 32;
            if (tid == 0) {
                unsigned long long packed =
                    ((unsigned long long)(unsigned)i << 48) |
                    ((unsigned long long)__float_as_uint(rv) << 16) |
                    (unsigned long long)(0xFFFFu ^ (unsigned)rp);
                __hip_atomic_store(sp + g, packed, __ATOMIC_RELAXED,
                                   __HIP_MEMORY_SCOPE_AGENT);
            }
            // spin until all 32 groups posted tag i (lane l mirrors l&31)
            const unsigned long long itag = (unsigned long long)(unsigned)i;
            unsigned long long q;
            for (;;) {
                q = __hip_atomic_load(sp + (tid & 31), __ATOMIC_RELAXED,
                                      __HIP_MEMORY_SCOPE_AGENT);
                if (__ballot((q >> 48) == itag) == ~0ULL) break;
            }
            // u64 max across the 32 slots (5 xor steps within each half)
#pragma unroll
            for (int s = 1; s <= 16; s <<= 1) {
                unsigned long long o = __shfl_xor(q, s, 64);
                q = (o > q) ? o : q;
            }
            unsigned widx = 0xFFFFu ^ (unsigned)(q & 0xFFFFull);
            widx = __builtin_amdgcn_readfirstlane(widx);
            cx = xb[widx * 3 + 0];
            cy = xb[widx * 3 + 1];
            cz = xb[widx * 3 + 2];
            if (g == 0 && tid == 0) {
                cent[b * NPOINT + i] = (int)widx;
                size_t o = ((size_t)b * NPOINT + i) * 3;
                out[o + 0] = cx; out[o + 1] = cy; out[o + 2] = cz;
            }
        }
    } else {
        if (!use_ft) return;
        // transpose feat (B,128,N) -> ft (B,N,128); 32x32 tile, 64 threads
        int t  = blk - FPS_NBLK;
        int b  = t >> 11;          // 2048 tiles per batch
        int r  = t & 2047;
        int ct = r >> 9;           // channel tile (4)
        int nt = r & 511;          // point tile (512)
        __shared__ float tile[32][33];
        int tx = tid & 31, ph = tid >> 5;   // ph in {0,1}
#pragma unroll
        for (int r2 = 0; r2 < 32; r2 += 2) {
            int row = r2 + ph;              // channel row
            tile[row][tx] =
                feat[((size_t)b * NCH + ct * 32 + row) * NPTS + nt * 32 + tx];
        }
        __syncthreads();
#pragma unroll
        for (int r2 = 0; r2 < 32; r2 += 2) {
            int row = r2 + ph;              // point row
            ft[((size_t)b * NPTS + nt * 32 + row) * NCH + ct * 32 + tx] =
                tile[tx][row];
        }
    }
}

// -------- kernel 2: ball query + grouped max pool ---------------------------
__global__ __launch_bounds__(256, 4)
void query_pool_kernel(const float* __restrict__ xyz,
                       const float* __restrict__ feat,
                       const float* __restrict__ ft,
                       const int* __restrict__ cent,
                       float* __restrict__ out_sub,   // (B,128,512)
                       int use_ft)
{
    const int tid  = threadIdx.x;
    const int widx = tid >> 6;
    const int lane = tid & 63;
    const int w = blockIdx.x * 4 + widx;   // 0..4095
    const int b = w >> 9;
    const int s = w & 511;

    const float* xb = xyz + (size_t)b * NPTS * 3;
    const int ci = cent[b * NPOINT + s];
    const float sx = xb[ci * 3 + 0];
    const float sy = xb[ci * 3 + 1];
    const float sz = xb[ci * 3 + 2];
    const float snorm = __fadd_rn(__fadd_rn(__fmul_rn(sx, sx),
                                            __fmul_rn(sy, sy)),
                                  __fmul_rn(sz, sz));

    __shared__ int lidx[4][KNBR];
    int found = 0;
    for (int base = 0; base < NPTS && found < KNBR; base += 64) {
        int j = base + lane;
        float dx = xb[j * 3 + 0];
        float dy = xb[j * 3 + 1];
        float dz = xb[j * 3 + 2];
        float dn = __fadd_rn(__fadd_rn(__fmul_rn(dx, dx),
                                       __fmul_rn(dy, dy)),
                             __fmul_rn(dz, dz));
        float dot = __fadd_rn(__fadd_rn(__fmul_rn(sx, dx),
                                        __fmul_rn(sy, dy)),
                              __fmul_rn(sz, dz));
        float d = __fadd_rn(__fadd_rn(__fmul_rn(-2.0f, dot), snorm), dn);
        bool inball = !(d > R2);
        unsigned long long mask = __ballot(inball);
        int before = (int)__popcll(mask & ((1ULL << lane) - 1ULL));
        int slot = found + before;
        if (inball && slot < KNBR) lidx[widx][slot] = j;
        found += (int)__popcll(mask);
    }
    int cnt = found < KNBR ? found : KNBR;   // cnt >= 1 (self in ball)
    __syncthreads();

    float a0 = -INFINITY, a1 = -INFINITY;
    if (use_ft) {
        for (int m = 0; m < cnt; ++m) {
            int i = lidx[widx][m];
            const float* row = ft + ((size_t)b * NPTS + i) * NCH;
            a0 = fmaxf(a0, row[lane]);
            a1 = fmaxf(a1, row[lane + 64]);
        }
    } else {
        for (int m = 0; m < cnt; ++m) {
            int i = lidx[widx][m];
            a0 = fmaxf(a0, feat[((size_t)b * NCH + lane) * NPTS + i]);
            a1 = fmaxf(a1, feat[((size_t)b * NCH + lane + 64) * NPTS + i]);
        }
    }
    out_sub[((size_t)b * NCH + lane) * NPOINT + s] = a0;
    out_sub[((size_t)b * NCH + lane + 64) * NPOINT + s] = a1;
}

extern "C" void kernel_launch(void* const* d_in, const int* in_sizes, int n_in,
                              void* d_out, int out_size, void* d_ws, size_t ws_size,
                              hipStream_t stream)
{
    const float* xyz  = (const float*)d_in[0];   // (8,16384,3)
    const float* feat = (const float*)d_in[1];   // (8,128,16384)
    float* out = (float*)d_out;                  // [new_xyz | sub_features]

    int*   cent = (int*)((char*)d_ws + CENT_OFF);
    unsigned long long* slots = (unsigned long long*)((char*)d_ws + SLOTS_OFF);
    float* ft   = (float*)((char*)d_ws + FT_OFF);
    const size_t need_ft = FT_OFF + (size_t)NB * NPTS * NCH * 4ull;
    int use_ft = (ws_size >= need_ft) ? 1 : 0;

    // reset sync slots to sentinel tag 0xFFFF (stream-ordered, capture-safe)
    hipMemsetAsync((char*)d_ws + SLOTS_OFF, 0xFF, NB * 64 * 8, stream);

    int nblocks1 = FPS_NBLK + (use_ft ? NB * (NCH / 32) * (NPTS / 32) : 0);
    hipLaunchKernelGGL(fps_transpose_kernel, dim3(nblocks1), dim3(64), 0, stream,
                       xyz, feat, out, cent, slots, ft, use_ft);

    hipLaunchKernelGGL(query_pool_kernel, dim3((NB * NPOINT) / 4), dim3(256), 0, stream,
                       xyz, feat, ft, cent, out + (size_t)NB * NPOINT * 3, use_ft);
}

// Round 4
// 1106.846 us; speedup vs baseline: 1.2792x; 1.2792x over previous
//
#include <hip/hip_runtime.h>
#include <stdint.h>
#include <math.h>

#define NB      8
#define NPTS    16384
#define NPOINT  512
#define NCH     128
#define KNBR    32
#define R2      0.04f

#define FPS_THR 512                  // 8 waves
#define PPT     (NPTS / FPS_THR)     // 32 points per thread

// ws layout
#define CENT_OFF 0                   // 8*512*4 = 16384 B
#define FT_OFF   16384               // transposed features

// argmax step over (value desc, index asc) using DPP permute (VALU latency)
#define DPP_ARG_STEP(v, p, CTRL) do {                                          \
    float _ov = __builtin_bit_cast(float, __builtin_amdgcn_update_dpp(         \
        __builtin_bit_cast(int, (v)), __builtin_bit_cast(int, (v)),            \
        (CTRL), 0xF, 0xF, false));                                             \
    int _op = __builtin_amdgcn_update_dpp((p), (p), (CTRL), 0xF, 0xF, false);  \
    bool _t = (_ov > (v)) || ((_ov == (v)) && (_op < (p)));                    \
    (v) = _t ? _ov : (v);                                                      \
    (p) = _t ? _op : (p);                                                      \
} while (0)

#define SHFL_ARG_STEP(v, p, XORAMT) do {                                       \
    float _ov = __shfl_xor((v), (XORAMT), 64);                                 \
    int   _op = __shfl_xor((p), (XORAMT), 64);                                 \
    bool _t = (_ov > (v)) || ((_ov == (v)) && (_op < (p)));                    \
    (v) = _t ? _ov : (v);                                                      \
    (p) = _t ? _op : (p);                                                      \
} while (0)

// -------- kernel 1: FPS (blocks 0..7, one CU per batch) + transpose ---------
// 8 waves * 32 pts/thread. Per iteration: local min-update + 16-lane DPP
// reduce -> 32 row partials in parity-buffered LDS -> ONE barrier -> all
// waves reduce the 32 partials (ds_read + 4 DPP + 1 shfl) -> uniform coords
// reload from global xyz (L1/L2-resident). No second barrier.
__global__
__attribute__((amdgpu_flat_work_group_size(FPS_THR, FPS_THR)))
__attribute__((amdgpu_waves_per_eu(2, 4)))
void fps_transpose_kernel(const float* __restrict__ xyz,
                          const float* __restrict__ feat,
                          float* __restrict__ out,     // new_xyz at [0,12288)
                          int* __restrict__ cent,      // ws: 8*512 ints
                          float* __restrict__ ft,      // ws: (B,N,128) fp32
                          int use_ft)
{
    const int blk = blockIdx.x;
    const int tid = threadIdx.x;

    if (blk < NB) {
        const int b = blk;
        const float* xb = xyz + (size_t)b * NPTS * 3;
        // 32 points/thread: p = k*512 + tid
        float px[PPT], py[PPT], pz[PPT], d[PPT];
#pragma unroll
        for (int k = 0; k < PPT; ++k) {
            int p = k * FPS_THR + tid;
            px[k] = xb[p * 3 + 0];
            py[k] = xb[p * 3 + 1];
            pz[k] = xb[p * 3 + 2];
            d[k] = 1e10f;
        }
        // parity-double-buffered partial slots (32 = 8 waves * 4 rows)
        __shared__ float s_v[2][32];
        __shared__ int   s_p[2][32];
        const int lane = tid & 63;
        const int wid  = tid >> 6;

        float cx = xb[0], cy = xb[1], cz = xb[2];
        if (tid == 0) {
            cent[b * NPOINT + 0] = 0;
            out[((size_t)b * NPOINT + 0) * 3 + 0] = cx;
            out[((size_t)b * NPOINT + 0) * 3 + 1] = cy;
            out[((size_t)b * NPOINT + 0) * 3 + 2] = cz;
        }

        for (int i = 1; i < NPOINT; ++i) {
            // phase 1: min-distance update, value-only tracking (bit-exact:
            // reference op order, no contraction)
            float vmax = -1.0f;
#pragma unroll
            for (int k = 0; k < PPT; ++k) {
                float dx = __fsub_rn(px[k], cx);
                float dy = __fsub_rn(py[k], cy);
                float dz = __fsub_rn(pz[k], cz);
                float dd = __fadd_rn(__fadd_rn(__fmul_rn(dx, dx),
                                               __fmul_rn(dy, dy)),
                                     __fmul_rn(dz, dz));
                float nd = fminf(d[k], dd);     // np.minimum, exact
                d[k] = nd;
                vmax = fmaxf(vmax, nd);
            }
            // recover earliest k with d[k]==vmax (fmax returns an operand, so
            // a match exists; descending scan -> smallest k wins; ascending k
            // == ascending global index -> reference tie-break)
            int bk = PPT - 1;
#pragma unroll
            for (int k = PPT - 2; k >= 0; --k) bk = (d[k] == vmax) ? k : bk;

            float rv = vmax;
            int   rp = bk * FPS_THR + tid;   // global point index
            // 16-lane row argmax (val desc, idx asc): 4 DPP steps, no shfl
            DPP_ARG_STEP(rv, rp, 0xB1);   // xor 1
            DPP_ARG_STEP(rv, rp, 0x4E);   // xor 2
            DPP_ARG_STEP(rv, rp, 0x141);  // row_half_mirror (4-grp pairs)
            DPP_ARG_STEP(rv, rp, 0x140);  // row_mirror      (8-grp pairs)
            const int par = i & 1;
            if ((lane & 15) == 0) {       // 4 row leaders per wave
                int slot = wid * 4 + (lane >> 4);
                s_v[par][slot] = rv;
                s_p[par][slot] = rp;
            }
            __syncthreads();              // the ONLY barrier per iteration
            // all waves redundantly reduce 32 partials:
            // lane reads slot lane&31; 4 DPP steps reduce each 16-slot half,
            // one xor-16 shfl combines the halves.
            float fv = s_v[par][lane & 31];
            int   fp = s_p[par][lane & 31];
            DPP_ARG_STEP(fv, fp, 0xB1);
            DPP_ARG_STEP(fv, fp, 0x4E);
            DPP_ARG_STEP(fv, fp, 0x141);
            DPP_ARG_STEP(fv, fp, 0x140);
            SHFL_ARG_STEP(fv, fp, 16);
            const int cur = __builtin_amdgcn_readfirstlane(fp);
            // uniform coords reload from global (L1/L2-resident, 192 KB/batch)
            cx = xb[cur * 3 + 0];
            cy = xb[cur * 3 + 1];
            cz = xb[cur * 3 + 2];
            if (tid == 0) {
                cent[b * NPOINT + i] = cur;
                size_t o = ((size_t)b * NPOINT + i) * 3;
                out[o + 0] = cx; out[o + 1] = cy; out[o + 2] = cz;
            }
        }
    } else {
        if (!use_ft) return;
        // transpose feat (B,128,N) -> ft (B,N,128); 32x32 tile, 512 threads
        int t  = blk - NB;
        int b  = t >> 11;          // 2048 tiles per batch
        int r  = t & 2047;
        int ct = r >> 9;           // channel tile (4)
        int nt = r & 511;          // point tile (512)
        __shared__ float tile[32][33];
        int tx = tid & 31, ty = tid >> 5;   // ty 0..15
        tile[ty][tx] =
            feat[((size_t)b * NCH + ct * 32 + ty) * NPTS + nt * 32 + tx];
        tile[ty + 16][tx] =
            feat[((size_t)b * NCH + ct * 32 + ty + 16) * NPTS + nt * 32 + tx];
        __syncthreads();
        ft[((size_t)b * NPTS + nt * 32 + ty) * NCH + ct * 32 + tx] =
            tile[tx][ty];
        ft[((size_t)b * NPTS + nt * 32 + ty + 16) * NCH + ct * 32 + tx] =
            tile[tx][ty + 16];
    }
}

// -------- kernel 2: ball query + grouped max pool ---------------------------
__global__ __launch_bounds__(256, 4)
void query_pool_kernel(const float* __restrict__ xyz,
                       const float* __restrict__ feat,
                       const float* __restrict__ ft,
                       const int* __restrict__ cent,
                       float* __restrict__ out_sub,   // (B,128,512)
                       int use_ft)
{
    const int tid  = threadIdx.x;
    const int widx = tid >> 6;
    const int lane = tid & 63;
    const int w = blockIdx.x * 4 + widx;   // 0..4095
    const int b = w >> 9;
    const int s = w & 511;

    const float* xb = xyz + (size_t)b * NPTS * 3;
    const int ci = cent[b * NPOINT + s];
    const float sx = xb[ci * 3 + 0];
    const float sy = xb[ci * 3 + 1];
    const float sz = xb[ci * 3 + 2];
    const float snorm = __fadd_rn(__fadd_rn(__fmul_rn(sx, sx),
                                            __fmul_rn(sy, sy)),
                                  __fmul_rn(sz, sz));

    __shared__ int lidx[4][KNBR];
    int found = 0;
    for (int base = 0; base < NPTS && found < KNBR; base += 64) {
        int j = base + lane;
        float dx = xb[j * 3 + 0];
        float dy = xb[j * 3 + 1];
        float dz = xb[j * 3 + 2];
        float dn = __fadd_rn(__fadd_rn(__fmul_rn(dx, dx),
                                       __fmul_rn(dy, dy)),
                             __fmul_rn(dz, dz));
        float dot = __fadd_rn(__fadd_rn(__fmul_rn(sx, dx),
                                        __fmul_rn(sy, dy)),
                              __fmul_rn(sz, dz));
        // reference order: d = -2*dot; d += snorm; d += dnorm
        float d = __fadd_rn(__fadd_rn(__fmul_rn(-2.0f, dot), snorm), dn);
        bool inball = !(d > R2);
        unsigned long long mask = __ballot(inball);
        int before = (int)__popcll(mask & ((1ULL << lane) - 1ULL));
        int slot = found + before;
        if (inball && slot < KNBR) lidx[widx][slot] = j;
        found += (int)__popcll(mask);
    }
    int cnt = found < KNBR ? found : KNBR;   // cnt >= 1 (self in ball)
    __syncthreads();

    float a0 = -INFINITY, a1 = -INFINITY;
    if (use_ft) {
        for (int m = 0; m < cnt; ++m) {
            int i = lidx[widx][m];
            const float* row = ft + ((size_t)b * NPTS + i) * NCH;
            a0 = fmaxf(a0, row[lane]);
            a1 = fmaxf(a1, row[lane + 64]);
        }
    } else {
        for (int m = 0; m < cnt; ++m) {
            int i = lidx[widx][m];
            a0 = fmaxf(a0, feat[((size_t)b * NCH + lane) * NPTS + i]);
            a1 = fmaxf(a1, feat[((size_t)b * NCH + lane + 64) * NPTS + i]);
        }
    }
    out_sub[((size_t)b * NCH + lane) * NPOINT + s] = a0;
    out_sub[((size_t)b * NCH + lane + 64) * NPOINT + s] = a1;
}

extern "C" void kernel_launch(void* const* d_in, const int* in_sizes, int n_in,
                              void* d_out, int out_size, void* d_ws, size_t ws_size,
                              hipStream_t stream)
{
    const float* xyz  = (const float*)d_in[0];   // (8,16384,3)
    const float* feat = (const float*)d_in[1];   // (8,128,16384)
    float* out = (float*)d_out;                  // [new_xyz | sub_features]

    int*   cent = (int*)((char*)d_ws + CENT_OFF);
    float* ft   = (float*)((char*)d_ws + FT_OFF);
    const size_t need_ft = FT_OFF + (size_t)NB * NPTS * NCH * 4ull;
    int use_ft = (ws_size >= need_ft) ? 1 : 0;

    int nblocks1 = NB + (use_ft ? NB * (NCH / 32) * (NPTS / 32) : 0);
    hipLaunchKernelGGL(fps_transpose_kernel, dim3(nblocks1), dim3(FPS_THR), 0, stream,
                       xyz, feat, out, cent, ft, use_ft);

    hipLaunchKernelGGL(query_pool_kernel, dim3((NB * NPOINT) / 4), dim3(256), 0, stream,
                       xyz, feat, ft, cent, out + (size_t)NB * NPOINT * 3, use_ft);
}